// Round 4
// baseline (1077.707 us; speedup 1.0000x reference)
//
#include <hip/hip_runtime.h>
#include <hip/hip_bf16.h>

// Problem constants (match reference setup_inputs)
#define NU 100000
#define NI 200000
#define NB 50000
#define D  64
#define D4B 256   // bytes per feature row

// Concatenated CSR row-space: 5 graph directions
#define B0 0
#define B1 (NU)
#define B2 (NU + NI)
#define B3 (2 * NU + NI)
#define B4 (2 * NU + NI + NB)
#define RTOT (2 * NU + NI + 2 * NB)   // 500000 rows total

// ======================= CSR build =======================

// fused degree histogram over all 5 directions
__global__ void hist_all_k(int* __restrict__ deg,
                           const int* __restrict__ ui_row, const int* __restrict__ ui_col,
                           const int* __restrict__ ub_row, const int* __restrict__ ub_col,
                           const int* __restrict__ bi_row,
                           int E_UI, int E_UB, int E_BI) {
    int i = blockIdx.x * blockDim.x + threadIdx.x;
    const int* p; int off;
    if (i < E_UI)                     { p = ui_row; off = B0; }
    else if (i < 2 * E_UI)            { p = ui_col; off = B1; i -= E_UI; }
    else if (i < 2 * E_UI + E_UB)     { p = ub_row; off = B2; i -= 2 * E_UI; }
    else if (i < 2 * E_UI + 2 * E_UB) { p = ub_col; off = B3; i -= 2 * E_UI + E_UB; }
    else if (i < 2 * E_UI + 2 * E_UB + E_BI) { p = bi_row; off = B4; i -= 2 * E_UI + 2 * E_UB; }
    else return;
    atomicAdd(&deg[off + p[i]], 1);
}

// scan pass A: per-block (2048 elems) sums
__global__ void scan_blocksum_k(const int* __restrict__ deg, int* __restrict__ blockSums, int n) {
    int tid = threadIdx.x;
    int base = blockIdx.x * 2048 + tid * 8;
    int sum = 0;
#pragma unroll
    for (int k = 0; k < 8; k++) {
        int idx = base + k;
        if (idx < n) sum += deg[idx];
    }
#pragma unroll
    for (int off = 32; off; off >>= 1) sum += __shfl_down(sum, off, 64);
    __shared__ int ws[4];
    if ((tid & 63) == 0) ws[tid >> 6] = sum;
    __syncthreads();
    if (tid == 0) blockSums[blockIdx.x] = ws[0] + ws[1] + ws[2] + ws[3];
}

// scan pass B: exclusive scan of block sums
__global__ void scan_offsets_k(int* __restrict__ blockSums, int* __restrict__ rowptr,
                               int numBlocks, int n) {
    if (threadIdx.x == 0 && blockIdx.x == 0) {
        int run = 0;
        for (int j = 0; j < numBlocks; j++) {
            int t = blockSums[j];
            blockSums[j] = run;
            run += t;
        }
        rowptr[n] = run;
    }
}

// scan pass C: write rowptr + cursor
__global__ void scan_write_k(const int* __restrict__ deg, const int* __restrict__ blockSums,
                             int* __restrict__ rowptr, int* __restrict__ cursor, int n) {
    int tid = threadIdx.x;
    int base = blockIdx.x * 2048 + tid * 8;
    int v[8];
    int sum = 0;
#pragma unroll
    for (int k = 0; k < 8; k++) {
        int idx = base + k;
        int d = (idx < n) ? deg[idx] : 0;
        v[k] = sum;
        sum += d;
    }
    int lane = tid & 63, wave = tid >> 6;
    int x = sum;
#pragma unroll
    for (int off = 1; off < 64; off <<= 1) {
        int y = __shfl_up(x, off, 64);
        if (lane >= off) x += y;
    }
    __shared__ int wsum[4];
    if (lane == 63) wsum[wave] = x;
    __syncthreads();
    int woff = 0;
    for (int w = 0; w < wave; w++) woff += wsum[w];
    int thrOff = blockSums[blockIdx.x] + woff + (x - sum);
#pragma unroll
    for (int k = 0; k < 8; k++) {
        int idx = base + k;
        if (idx < n) {
            int val = thrOff + v[k];
            rowptr[idx] = val;
            cursor[idx] = val;
        }
    }
}

// fused edge placement; stores BYTE offsets (src index << 8)
__global__ void place_all_k(int* __restrict__ cursor, int* __restrict__ ebuf,
                            const int* __restrict__ ui_row, const int* __restrict__ ui_col,
                            const int* __restrict__ ub_row, const int* __restrict__ ub_col,
                            const int* __restrict__ bi_row, const int* __restrict__ bi_col,
                            int E_UI, int E_UB, int E_BI) {
    int i = blockIdx.x * blockDim.x + threadIdx.x;
    const int* dI; const int* sI; int off;
    if (i < E_UI)                     { dI = ui_row; sI = ui_col; off = B0; }
    else if (i < 2 * E_UI)            { dI = ui_col; sI = ui_row; off = B1; i -= E_UI; }
    else if (i < 2 * E_UI + E_UB)     { dI = ub_row; sI = ub_col; off = B2; i -= 2 * E_UI; }
    else if (i < 2 * E_UI + 2 * E_UB) { dI = ub_col; sI = ub_row; off = B3; i -= 2 * E_UI + E_UB; }
    else if (i < 2 * E_UI + 2 * E_UB + E_BI) { dI = bi_row; sI = bi_col; off = B4; i -= 2 * E_UI + 2 * E_UB; }
    else return;
    int pos = atomicAdd(&cursor[off + dI[i]], 1);
    ebuf[pos] = sI[i] << 8;
}

// ======================= pull machinery =======================
// wave per row; lane l: group g=l>>4 handles a CONTIGUOUS quarter of the edge
// range (int2 index loads), q=(l&15)*16B is the dim-quad byte offset.

__device__ __forceinline__ float4 ld4(const char* p) {
    return *reinterpret_cast<const float4*>(p);
}

__device__ __forceinline__ void xreduce4(float4& a) {
    a.x += __shfl_xor(a.x, 16, 64); a.y += __shfl_xor(a.y, 16, 64);
    a.z += __shfl_xor(a.z, 16, 64); a.w += __shfl_xor(a.w, 16, 64);
    a.x += __shfl_xor(a.x, 32, 64); a.y += __shfl_xor(a.y, 32, 64);
    a.z += __shfl_xor(a.z, 32, 64); a.w += __shfl_xor(a.w, 32, 64);
}

__device__ __forceinline__ float rowsum16(float s) {
#pragma unroll
    for (int off = 1; off < 16; off <<= 1) s += __shfl_xor(s, off, 64);
    return s;
}

// sum of feature rows at byte-offsets ebuf[s..e) from baseq (= src + q16)
__device__ __forceinline__ float4 pull_edges(int s, int e, int g,
                                             const int* __restrict__ ebuf,
                                             const char* __restrict__ baseq) {
    int cnt = e - s;
    int q0 = cnt >> 2, rem = cnt & 3;
    int myCnt = q0 + (g < rem ? 1 : 0);
    int j = s + g * q0 + (g < rem ? g : rem);
    int jend = j + myCnt;
    float4 acc = {0.f, 0.f, 0.f, 0.f};
    if ((j & 1) && j < jend) {  // align for int2 index loads
        float4 v = ld4(baseq + (unsigned)ebuf[j]);
        acc.x += v.x; acc.y += v.y; acc.z += v.z; acc.w += v.w;
        j++;
    }
    for (; j + 1 < jend; j += 2) {
        int2 c2 = *reinterpret_cast<const int2*>(ebuf + j);
        float4 v0 = ld4(baseq + (unsigned)c2.x);
        float4 v1 = ld4(baseq + (unsigned)c2.y);
        acc.x += v0.x; acc.y += v0.y; acc.z += v0.z; acc.w += v0.w;
        acc.x += v1.x; acc.y += v1.y; acc.z += v1.z; acc.w += v1.w;
    }
    if (j < jend) {
        float4 v = ld4(baseq + (unsigned)ebuf[j]);
        acc.x += v.x; acc.y += v.y; acc.z += v.z; acc.w += v.w;
    }
    xreduce4(acc);
    return acc;
}

// stage1: all four layer-1 pulls fused (rows 0..B4 of the concatenated CSR)
__global__ void stage1_k(const int* __restrict__ rowptr, const int* __restrict__ ebuf,
                         const float* __restrict__ U, const float* __restrict__ I,
                         const float* __restrict__ Bf,
                         float* __restrict__ f1u_ui, float* __restrict__ f1i_ui,
                         float* __restrict__ f1u_ub, float* __restrict__ f1b_ub) {
    int gr = blockIdx.x * 4 + (threadIdx.x >> 6);
    if (gr >= B4) return;
    int lane = threadIdx.x & 63;
    int g = lane >> 4, q16 = (lane & 15) << 4;
    const float* src; float* dst; int row;
    if (gr < B1)      { src = I;  dst = f1u_ui; row = gr; }
    else if (gr < B2) { src = U;  dst = f1i_ui; row = gr - B1; }
    else if (gr < B3) { src = Bf; dst = f1u_ub; row = gr - B2; }
    else              { src = U;  dst = f1b_ub; row = gr - B3; }
    int s = rowptr[gr], e = rowptr[gr + 1];
    float4 acc = pull_edges(s, e, g, ebuf, (const char*)src + q16);
    if (g == 0)
        *reinterpret_cast<float4*>((char*)dst + (size_t)row * D4B + q16) = acc;
}

// layer-2 pull + finalize body
__device__ __forceinline__ void fin_store(float4 acc, const float* self, const float* basef,
                                          float* out, size_t rowOffD, size_t rowOffOut,
                                          int lane) {
    int q = (lane & 15) << 2;
    const float4 v1 = *reinterpret_cast<const float4*>(self + rowOffD + q);
    float s1 = v1.x * v1.x + v1.y * v1.y + v1.z * v1.z + v1.w * v1.w;
    float s2 = acc.x * acc.x + acc.y * acc.y + acc.z * acc.z + acc.w * acc.w;
    s1 = rowsum16(s1);
    s2 = rowsum16(s2);
    float i1 = 1.0f / fmaxf(sqrtf(s1), 1e-12f);
    float i2 = 1.0f / fmaxf(sqrtf(s2), 1e-12f);
    const float4 b4 = *reinterpret_cast<const float4*>(basef + rowOffD + q);
    float4 o;
    o.x = b4.x + v1.x * i1 + acc.x * i2;
    o.y = b4.y + v1.y * i1 + acc.y * i2;
    o.z = b4.z + v1.z * i1 + acc.z * i2;
    o.w = b4.w + v1.w * i1 + acc.w * i2;
    if ((lane >> 4) == 0)
        *reinterpret_cast<float4*>(out + rowOffOut + q) = o;
}

// stage2a: ui-user, ub-user, ub-bundle finalize fused
__global__ void stage2a_k(const int* __restrict__ rowptr, const int* __restrict__ ebuf,
                          const float* __restrict__ U, const float* __restrict__ Bf,
                          const float* __restrict__ f1u_ui, const float* __restrict__ f1i_ui,
                          const float* __restrict__ f1u_ub, const float* __restrict__ f1b_ub,
                          float* __restrict__ outU, float* __restrict__ outB) {
    int t = blockIdx.x * 4 + (threadIdx.x >> 6);
    if (t >= 2 * NU + NB) return;
    int lane = threadIdx.x & 63;
    int g = lane >> 4, q16 = (lane & 15) << 4;
    int cr, row; const float* src; const float* self; const float* basef; float* out;
    if (t < NU)          { cr = t;               src = f1i_ui; self = f1u_ui; basef = U;  out = outU;      row = t; }
    else if (t < 2 * NU) { cr = B2 + t - NU;     src = f1b_ub; self = f1u_ub; basef = U;  out = outU + 64; row = t - NU; }
    else                 { cr = B3 + t - 2 * NU; src = f1u_ub; self = f1b_ub; basef = Bf; out = outB + 64; row = t - 2 * NU; }
    int s = rowptr[cr], e = rowptr[cr + 1];
    float4 acc = pull_edges(s, e, g, ebuf, (const char*)src + q16);
    fin_store(acc, self, basef, out, (size_t)row * D, (size_t)row * 128, lane);
}

// stage2b: ui-item finalize, acc_i written IN PLACE over f1i_ui
__global__ void stage2b_k(const int* __restrict__ rowptr, const int* __restrict__ ebuf,
                          const float* __restrict__ I, const float* __restrict__ f1u_ui,
                          float* __restrict__ f1i_ui) {
    int t = blockIdx.x * 4 + (threadIdx.x >> 6);
    if (t >= NI) return;
    int lane = threadIdx.x & 63;
    int g = lane >> 4, q16 = (lane & 15) << 4;
    int s = rowptr[B1 + t], e = rowptr[B1 + t + 1];
    float4 acc = pull_edges(s, e, g, ebuf, (const char*)f1u_ui + q16);
    fin_store(acc, f1i_ui, I, f1i_ui, (size_t)t * D, (size_t)t * D, lane);
}

// stage3: weighted bi aggregation -> outB[:,0:64]
__global__ void stage3_k(const int* __restrict__ rowptr, const int* __restrict__ ebuf,
                         const float* __restrict__ acc_i, float* __restrict__ outB) {
    int t = blockIdx.x * 4 + (threadIdx.x >> 6);
    if (t >= NB) return;
    int lane = threadIdx.x & 63;
    int g = lane >> 4, q16 = (lane & 15) << 4;
    int s = rowptr[B4 + t], e = rowptr[B4 + t + 1];
    float4 acc = pull_edges(s, e, g, ebuf, (const char*)acc_i + q16);
    float w = 1.0f / ((float)(e - s) + 1e-8f);
    acc.x *= w; acc.y *= w; acc.z *= w; acc.w *= w;
    if (g == 0)
        *reinterpret_cast<float4*>(outB + (size_t)t * 128 + ((lane & 15) << 2)) = acc;
}

extern "C" void kernel_launch(void* const* d_in, const int* in_sizes, int n_in,
                              void* d_out, int out_size, void* d_ws, size_t ws_size,
                              hipStream_t stream) {
    const float* U = (const float*)d_in[0];
    const float* I = (const float*)d_in[1];
    const float* B = (const float*)d_in[2];
    const int* ui_row = (const int*)d_in[3];
    const int* ui_col = (const int*)d_in[4];
    const int* ub_row = (const int*)d_in[5];
    const int* ub_col = (const int*)d_in[6];
    const int* bi_row = (const int*)d_in[7];
    const int* bi_col = (const int*)d_in[8];
    const int E_UI = in_sizes[3], E_UB = in_sizes[5], E_BI = in_sizes[7];

    // workspace layout (~139 MB):
    float* f1u_ui = (float*)d_ws;                       // NU*D
    float* f1i_ui = f1u_ui + (size_t)NU * D;            // NI*D (becomes acc_i)
    float* f1u_ub = f1i_ui + (size_t)NI * D;            // NU*D
    float* f1b_ub = f1u_ub + (size_t)NU * D;            // NB*D
    int* deg       = (int*)(f1b_ub + (size_t)NB * D);   // RTOT
    int* rowptr    = deg + RTOT;                        // RTOT+1
    int* cursor    = rowptr + (RTOT + 1);               // RTOT
    int* blockSums = cursor + RTOT;                     // 256
    int* ebuf      = blockSums + 256;                   // 2*E_UI+2*E_UB+E_BI

    float* outU = (float*)d_out;            // NU x 128 (IL_u | BL_u)
    float* outB = outU + (size_t)NU * 128;  // NB x 128 (IL_b | BL_b)

    const int T = 256;
    const int SB = (RTOT + 2047) / 2048;
    const int ETOT = 2 * E_UI + 2 * E_UB + E_BI;

    // ---- CSR build ----
    hipMemsetAsync(deg, 0, RTOT * sizeof(int), stream);
    hist_all_k<<<(ETOT + T - 1) / T, T, 0, stream>>>(deg, ui_row, ui_col, ub_row, ub_col,
                                                     bi_row, E_UI, E_UB, E_BI);
    scan_blocksum_k<<<SB, T, 0, stream>>>(deg, blockSums, RTOT);
    scan_offsets_k<<<1, 64, 0, stream>>>(blockSums, rowptr, SB, RTOT);
    scan_write_k<<<SB, T, 0, stream>>>(deg, blockSums, rowptr, cursor, RTOT);
    place_all_k<<<(ETOT + T - 1) / T, T, 0, stream>>>(cursor, ebuf, ui_row, ui_col, ub_row,
                                                      ub_col, bi_row, bi_col, E_UI, E_UB, E_BI);

    // ---- stage1: all four layer-1 pulls ----
    stage1_k<<<(B4 + 3) / 4, T, 0, stream>>>(rowptr, ebuf, U, I, B,
                                             f1u_ui, f1i_ui, f1u_ub, f1b_ub);
    // ---- stage2a: ui-user, ub-user, ub-bundle finalize ----
    stage2a_k<<<(2 * NU + NB + 3) / 4, T, 0, stream>>>(rowptr, ebuf, U, B,
                                                       f1u_ui, f1i_ui, f1u_ub, f1b_ub,
                                                       outU, outB);
    // ---- stage2b: ui-item finalize (in-place acc_i) ----
    stage2b_k<<<(NI + 3) / 4, T, 0, stream>>>(rowptr, ebuf, I, f1u_ui, f1i_ui);
    // ---- stage3: weighted bi aggregation ----
    stage3_k<<<(NB + 3) / 4, T, 0, stream>>>(rowptr, ebuf, f1i_ui, outB);
}

// Round 5
// 858.042 us; speedup vs baseline: 1.2560x; 1.2560x over previous
//
#include <hip/hip_runtime.h>
#include <hip/hip_bf16.h>

// Problem constants (match reference setup_inputs)
#define NU 100000
#define NI 200000
#define NB 50000
#define D  64
#define D4B 256   // bytes per feature row

// Concatenated CSR row-space: 5 graph directions
#define B0 0
#define B1 (NU)
#define B2 (NU + NI)
#define B3 (2 * NU + NI)
#define B4 (2 * NU + NI + NB)
#define RTOT (2 * NU + NI + 2 * NB)   // 500000 rows total

// Bucketing for the two-phase edge sort
#define BKT_SHIFT 12
#define ROWS_PER_BKT 4096
#define NBKT ((RTOT + ROWS_PER_BKT - 1) / ROWS_PER_BKT)   // 123
#define TILE 4096
#define EPT (TILE / 256)

// ======================= CSR build =======================

// fused degree histogram over all 5 directions
__global__ void hist_all_k(int* __restrict__ deg,
                           const int* __restrict__ ui_row, const int* __restrict__ ui_col,
                           const int* __restrict__ ub_row, const int* __restrict__ ub_col,
                           const int* __restrict__ bi_row,
                           int E_UI, int E_UB, int E_BI) {
    int i = blockIdx.x * blockDim.x + threadIdx.x;
    const int* p; int off;
    if (i < E_UI)                     { p = ui_row; off = B0; }
    else if (i < 2 * E_UI)            { p = ui_col; off = B1; i -= E_UI; }
    else if (i < 2 * E_UI + E_UB)     { p = ub_row; off = B2; i -= 2 * E_UI; }
    else if (i < 2 * E_UI + 2 * E_UB) { p = ub_col; off = B3; i -= 2 * E_UI + E_UB; }
    else if (i < 2 * E_UI + 2 * E_UB + E_BI) { p = bi_row; off = B4; i -= 2 * E_UI + 2 * E_UB; }
    else return;
    atomicAdd(&deg[off + p[i]], 1);
}

// scan pass A: per-block (2048 elems) sums
__global__ void scan_blocksum_k(const int* __restrict__ deg, int* __restrict__ blockSums, int n) {
    int tid = threadIdx.x;
    int base = blockIdx.x * 2048 + tid * 8;
    int sum = 0;
#pragma unroll
    for (int k = 0; k < 8; k++) {
        int idx = base + k;
        if (idx < n) sum += deg[idx];
    }
#pragma unroll
    for (int off = 32; off; off >>= 1) sum += __shfl_down(sum, off, 64);
    __shared__ int ws[4];
    if ((tid & 63) == 0) ws[tid >> 6] = sum;
    __syncthreads();
    if (tid == 0) blockSums[blockIdx.x] = ws[0] + ws[1] + ws[2] + ws[3];
}

// scan pass B: exclusive scan of block sums — single wave, shfl scan
__global__ void scan_offsets_k(int* __restrict__ blockSums, int* __restrict__ rowptr,
                               int numBlocks, int n) {
    int lane = threadIdx.x;  // 64 threads
    int nchunk = (numBlocks + 63) / 64;
    int idx0 = lane * nchunk;
    int vals[8];  // nchunk <= 8 for numBlocks <= 512
    int s = 0;
#pragma unroll 4
    for (int k = 0; k < nchunk; k++) {
        int id = idx0 + k;
        vals[k] = (id < numBlocks) ? blockSums[id] : 0;
        s += vals[k];
    }
    int x = s;
#pragma unroll
    for (int off = 1; off < 64; off <<= 1) {
        int y = __shfl_up(x, off, 64);
        if (lane >= off) x += y;
    }
    int excl = x - s;
#pragma unroll 4
    for (int k = 0; k < nchunk; k++) {
        int id = idx0 + k;
        if (id < numBlocks) blockSums[id] = excl;
        excl += vals[k];
    }
    if (lane == 63) rowptr[n] = x;
}

// scan pass C: write rowptr
__global__ void scan_write_k(const int* __restrict__ deg, const int* __restrict__ blockSums,
                             int* __restrict__ rowptr, int n) {
    int tid = threadIdx.x;
    int base = blockIdx.x * 2048 + tid * 8;
    int v[8];
    int sum = 0;
#pragma unroll
    for (int k = 0; k < 8; k++) {
        int idx = base + k;
        int d = (idx < n) ? deg[idx] : 0;
        v[k] = sum;
        sum += d;
    }
    int lane = tid & 63, wave = tid >> 6;
    int x = sum;
#pragma unroll
    for (int off = 1; off < 64; off <<= 1) {
        int y = __shfl_up(x, off, 64);
        if (lane >= off) x += y;
    }
    __shared__ int wsum[4];
    if (lane == 63) wsum[wave] = x;
    __syncthreads();
    int woff = 0;
    for (int w = 0; w < wave; w++) woff += wsum[w];
    int thrOff = blockSums[blockIdx.x] + woff + (x - sum);
#pragma unroll
    for (int k = 0; k < 8; k++) {
        int idx = base + k;
        if (idx < n) rowptr[idx] = thrOff + v[k];
    }
}

// init per-bucket append cursors: gcur[b] = rowptr[b*4096]
__global__ void initgcur_k(const int* __restrict__ rowptr, int* __restrict__ gcur) {
    int b = threadIdx.x;
    if (b < 128) {
        int r = b << BKT_SHIFT;
        gcur[b] = rowptr[r < RTOT ? r : RTOT];
    }
}

// edge decode: global edge id -> (global dst row, src index)
__device__ __forceinline__ void decode_edge(int i,
        const int* __restrict__ ui_row, const int* __restrict__ ui_col,
        const int* __restrict__ ub_row, const int* __restrict__ ub_col,
        const int* __restrict__ bi_row, const int* __restrict__ bi_col,
        int E_UI, int E_UB, int E_BI, int& gdst, int& src) {
    if (i < E_UI)                     { gdst = B0 + ui_row[i]; src = ui_col[i]; }
    else if (i < 2 * E_UI)            { int j = i - E_UI; gdst = B1 + ui_col[j]; src = ui_row[j]; }
    else if (i < 2 * E_UI + E_UB)     { int j = i - 2 * E_UI; gdst = B2 + ub_row[j]; src = ub_col[j]; }
    else if (i < 2 * E_UI + 2 * E_UB) { int j = i - 2 * E_UI - E_UB; gdst = B3 + ub_col[j]; src = ub_row[j]; }
    else                              { int j = i - 2 * E_UI - 2 * E_UB; gdst = B4 + bi_row[j]; src = bi_col[j]; }
}

// Phase A: tile-local counting sort by coarse bucket, run-contiguous append to bbuf.
// bbuf entry: (src << 12) | (gdst & 4095)
__global__ __launch_bounds__(256) void binA_k(
        const int* __restrict__ ui_row, const int* __restrict__ ui_col,
        const int* __restrict__ ub_row, const int* __restrict__ ub_col,
        const int* __restrict__ bi_row, const int* __restrict__ bi_col,
        int E_UI, int E_UB, int E_BI, int ETOT,
        int* __restrict__ gcur, int* __restrict__ bbuf) {
    __shared__ int hist[NBKT], runStart[NBKT], gbase[NBKT], cnt2[NBKT];
    __shared__ int ord[TILE];
    __shared__ int gpos[TILE];
    int tid = threadIdx.x;
    for (int b = tid; b < NBKT; b += 256) { hist[b] = 0; cnt2[b] = 0; }
    __syncthreads();
    int base = blockIdx.x * TILE;
    // pass 1: bucket histogram
#pragma unroll
    for (int k = 0; k < EPT; k++) {
        int i = base + k * 256 + tid;
        if (i < ETOT) {
            int gdst, src;
            decode_edge(i, ui_row, ui_col, ub_row, ub_col, bi_row, bi_col,
                        E_UI, E_UB, E_BI, gdst, src);
            atomicAdd(&hist[gdst >> BKT_SHIFT], 1);
        }
    }
    __syncthreads();
    if (tid == 0) {
        int run = 0;
        for (int b = 0; b < NBKT; b++) { runStart[b] = run; run += hist[b]; }
    }
    __syncthreads();
    if (tid < NBKT && hist[tid] > 0) gbase[tid] = atomicAdd(&gcur[tid], hist[tid]);
    __syncthreads();
    // pass 2: place into LDS ordered buffer
#pragma unroll
    for (int k = 0; k < EPT; k++) {
        int i = base + k * 256 + tid;
        if (i < ETOT) {
            int gdst, src;
            decode_edge(i, ui_row, ui_col, ub_row, ub_col, bi_row, bi_col,
                        E_UI, E_UB, E_BI, gdst, src);
            int b = gdst >> BKT_SHIFT;
            int loc = runStart[b] + atomicAdd(&cnt2[b], 1);
            ord[loc] = (src << BKT_SHIFT) | (gdst & (ROWS_PER_BKT - 1));
            gpos[loc] = gbase[b] + (loc - runStart[b]);
        }
    }
    __syncthreads();
    // pass 3: run-contiguous copy out
    int tcnt = runStart[NBKT - 1] + hist[NBKT - 1];
    for (int i = tid; i < tcnt; i += 256) bbuf[gpos[i]] = ord[i];
}

// Phase B: per-bucket row placement; scatter confined to the bucket's ebuf window.
// ebuf entry: src byte offset (src * 256)
__global__ __launch_bounds__(1024) void binB_k(const int* __restrict__ rowptr,
                                               const int* __restrict__ bbuf,
                                               int* __restrict__ ebuf) {
    __shared__ int lcur[ROWS_PER_BKT];
    int bkt = blockIdx.x;
    int rbase = bkt << BKT_SHIFT;
    int rend = rbase + ROWS_PER_BKT;
    if (rend > RTOT) rend = RTOT;
    int nrows = rend - rbase;
    for (int r = threadIdx.x; r < nrows; r += 1024) lcur[r] = rowptr[rbase + r];
    __syncthreads();
    int s = rowptr[rbase], e = rowptr[rend];
    for (int i = s + (int)threadIdx.x; i < e; i += 1024) {
        int entry = bbuf[i];
        int r = entry & (ROWS_PER_BKT - 1);
        int pos = atomicAdd(&lcur[r], 1);
        ebuf[pos] = (entry >> BKT_SHIFT) << 8;
    }
}

// ======================= pull machinery =======================
// wave per row; lane l: group g=l>>4 handles a CONTIGUOUS quarter of the edge
// range (int2 index loads), q=(l&15)*16B is the dim-quad byte offset.

__device__ __forceinline__ float4 ld4(const char* p) {
    return *reinterpret_cast<const float4*>(p);
}

__device__ __forceinline__ void xreduce4(float4& a) {
    a.x += __shfl_xor(a.x, 16, 64); a.y += __shfl_xor(a.y, 16, 64);
    a.z += __shfl_xor(a.z, 16, 64); a.w += __shfl_xor(a.w, 16, 64);
    a.x += __shfl_xor(a.x, 32, 64); a.y += __shfl_xor(a.y, 32, 64);
    a.z += __shfl_xor(a.z, 32, 64); a.w += __shfl_xor(a.w, 32, 64);
}

__device__ __forceinline__ float rowsum16(float s) {
#pragma unroll
    for (int off = 1; off < 16; off <<= 1) s += __shfl_xor(s, off, 64);
    return s;
}

__device__ __forceinline__ float4 pull_edges(int s, int e, int g,
                                             const int* __restrict__ ebuf,
                                             const char* __restrict__ baseq) {
    int cnt = e - s;
    int q0 = cnt >> 2, rem = cnt & 3;
    int myCnt = q0 + (g < rem ? 1 : 0);
    int j = s + g * q0 + (g < rem ? g : rem);
    int jend = j + myCnt;
    float4 acc = {0.f, 0.f, 0.f, 0.f};
    if ((j & 1) && j < jend) {
        float4 v = ld4(baseq + (unsigned)ebuf[j]);
        acc.x += v.x; acc.y += v.y; acc.z += v.z; acc.w += v.w;
        j++;
    }
    for (; j + 1 < jend; j += 2) {
        int2 c2 = *reinterpret_cast<const int2*>(ebuf + j);
        float4 v0 = ld4(baseq + (unsigned)c2.x);
        float4 v1 = ld4(baseq + (unsigned)c2.y);
        acc.x += v0.x; acc.y += v0.y; acc.z += v0.z; acc.w += v0.w;
        acc.x += v1.x; acc.y += v1.y; acc.z += v1.z; acc.w += v1.w;
    }
    if (j < jend) {
        float4 v = ld4(baseq + (unsigned)ebuf[j]);
        acc.x += v.x; acc.y += v.y; acc.z += v.z; acc.w += v.w;
    }
    xreduce4(acc);
    return acc;
}

// stage1: all four layer-1 pulls fused
__global__ void stage1_k(const int* __restrict__ rowptr, const int* __restrict__ ebuf,
                         const float* __restrict__ U, const float* __restrict__ I,
                         const float* __restrict__ Bf,
                         float* __restrict__ f1u_ui, float* __restrict__ f1i_ui,
                         float* __restrict__ f1u_ub, float* __restrict__ f1b_ub) {
    int gr = blockIdx.x * 4 + (threadIdx.x >> 6);
    if (gr >= B4) return;
    int lane = threadIdx.x & 63;
    int g = lane >> 4, q16 = (lane & 15) << 4;
    const float* src; float* dst; int row;
    if (gr < B1)      { src = I;  dst = f1u_ui; row = gr; }
    else if (gr < B2) { src = U;  dst = f1i_ui; row = gr - B1; }
    else if (gr < B3) { src = Bf; dst = f1u_ub; row = gr - B2; }
    else              { src = U;  dst = f1b_ub; row = gr - B3; }
    int s = rowptr[gr], e = rowptr[gr + 1];
    float4 acc = pull_edges(s, e, g, ebuf, (const char*)src + q16);
    if (g == 0)
        *reinterpret_cast<float4*>((char*)dst + (size_t)row * D4B + q16) = acc;
}

__device__ __forceinline__ void fin_store(float4 acc, const float* self, const float* basef,
                                          float* out, size_t rowOffD, size_t rowOffOut,
                                          int lane) {
    int q = (lane & 15) << 2;
    const float4 v1 = *reinterpret_cast<const float4*>(self + rowOffD + q);
    float s1 = v1.x * v1.x + v1.y * v1.y + v1.z * v1.z + v1.w * v1.w;
    float s2 = acc.x * acc.x + acc.y * acc.y + acc.z * acc.z + acc.w * acc.w;
    s1 = rowsum16(s1);
    s2 = rowsum16(s2);
    float i1 = 1.0f / fmaxf(sqrtf(s1), 1e-12f);
    float i2 = 1.0f / fmaxf(sqrtf(s2), 1e-12f);
    const float4 b4 = *reinterpret_cast<const float4*>(basef + rowOffD + q);
    float4 o;
    o.x = b4.x + v1.x * i1 + acc.x * i2;
    o.y = b4.y + v1.y * i1 + acc.y * i2;
    o.z = b4.z + v1.z * i1 + acc.z * i2;
    o.w = b4.w + v1.w * i1 + acc.w * i2;
    if ((lane >> 4) == 0)
        *reinterpret_cast<float4*>(out + rowOffOut + q) = o;
}

// stage2a: ui-user, ub-user, ub-bundle finalize fused
__global__ void stage2a_k(const int* __restrict__ rowptr, const int* __restrict__ ebuf,
                          const float* __restrict__ U, const float* __restrict__ Bf,
                          const float* __restrict__ f1u_ui, const float* __restrict__ f1i_ui,
                          const float* __restrict__ f1u_ub, const float* __restrict__ f1b_ub,
                          float* __restrict__ outU, float* __restrict__ outB) {
    int t = blockIdx.x * 4 + (threadIdx.x >> 6);
    if (t >= 2 * NU + NB) return;
    int lane = threadIdx.x & 63;
    int g = lane >> 4, q16 = (lane & 15) << 4;
    int cr, row; const float* src; const float* self; const float* basef; float* out;
    if (t < NU)          { cr = t;               src = f1i_ui; self = f1u_ui; basef = U;  out = outU;      row = t; }
    else if (t < 2 * NU) { cr = B2 + t - NU;     src = f1b_ub; self = f1u_ub; basef = U;  out = outU + 64; row = t - NU; }
    else                 { cr = B3 + t - 2 * NU; src = f1u_ub; self = f1b_ub; basef = Bf; out = outB + 64; row = t - 2 * NU; }
    int s = rowptr[cr], e = rowptr[cr + 1];
    float4 acc = pull_edges(s, e, g, ebuf, (const char*)src + q16);
    fin_store(acc, self, basef, out, (size_t)row * D, (size_t)row * 128, lane);
}

// stage2b: ui-item finalize, acc_i written IN PLACE over f1i_ui
__global__ void stage2b_k(const int* __restrict__ rowptr, const int* __restrict__ ebuf,
                          const float* __restrict__ I, const float* __restrict__ f1u_ui,
                          float* __restrict__ f1i_ui) {
    int t = blockIdx.x * 4 + (threadIdx.x >> 6);
    if (t >= NI) return;
    int lane = threadIdx.x & 63;
    int g = lane >> 4, q16 = (lane & 15) << 4;
    int s = rowptr[B1 + t], e = rowptr[B1 + t + 1];
    float4 acc = pull_edges(s, e, g, ebuf, (const char*)f1u_ui + q16);
    fin_store(acc, f1i_ui, I, f1i_ui, (size_t)t * D, (size_t)t * D, lane);
}

// stage3: weighted bi aggregation -> outB[:,0:64]
__global__ void stage3_k(const int* __restrict__ rowptr, const int* __restrict__ ebuf,
                         const float* __restrict__ acc_i, float* __restrict__ outB) {
    int t = blockIdx.x * 4 + (threadIdx.x >> 6);
    if (t >= NB) return;
    int lane = threadIdx.x & 63;
    int g = lane >> 4, q16 = (lane & 15) << 4;
    int s = rowptr[B4 + t], e = rowptr[B4 + t + 1];
    float4 acc = pull_edges(s, e, g, ebuf, (const char*)acc_i + q16);
    float w = 1.0f / ((float)(e - s) + 1e-8f);
    acc.x *= w; acc.y *= w; acc.z *= w; acc.w *= w;
    if (g == 0)
        *reinterpret_cast<float4*>(outB + (size_t)t * 128 + ((lane & 15) << 2)) = acc;
}

extern "C" void kernel_launch(void* const* d_in, const int* in_sizes, int n_in,
                              void* d_out, int out_size, void* d_ws, size_t ws_size,
                              hipStream_t stream) {
    const float* U = (const float*)d_in[0];
    const float* I = (const float*)d_in[1];
    const float* B = (const float*)d_in[2];
    const int* ui_row = (const int*)d_in[3];
    const int* ui_col = (const int*)d_in[4];
    const int* ub_row = (const int*)d_in[5];
    const int* ub_col = (const int*)d_in[6];
    const int* bi_row = (const int*)d_in[7];
    const int* bi_col = (const int*)d_in[8];
    const int E_UI = in_sizes[3], E_UB = in_sizes[5], E_BI = in_sizes[7];
    const int ETOT = 2 * E_UI + 2 * E_UB + E_BI;

    // workspace layout (~137 MB):
    float* f1u_ui = (float*)d_ws;                       // NU*D (first 18MB doubles as bbuf pre-stage1)
    float* f1i_ui = f1u_ui + (size_t)NU * D;            // NI*D (becomes acc_i)
    float* f1u_ub = f1i_ui + (size_t)NI * D;            // NU*D
    float* f1b_ub = f1u_ub + (size_t)NU * D;            // NB*D
    int* deg       = (int*)(f1b_ub + (size_t)NB * D);   // RTOT
    int* rowptr    = deg + RTOT;                        // RTOT+1
    int* blockSums = rowptr + (RTOT + 1);               // 256
    int* gcur      = blockSums + 256;                   // 128
    int* ebuf      = gcur + 128;                        // ETOT
    int* bbuf      = (int*)f1u_ui;                      // ETOT (aliases f1u_ui, dead by stage1)

    float* outU = (float*)d_out;            // NU x 128 (IL_u | BL_u)
    float* outB = outU + (size_t)NU * 128;  // NB x 128 (IL_b | BL_b)

    const int T = 256;
    const int SB = (RTOT + 2047) / 2048;

    // ---- CSR build ----
    hipMemsetAsync(deg, 0, RTOT * sizeof(int), stream);
    hist_all_k<<<(ETOT + T - 1) / T, T, 0, stream>>>(deg, ui_row, ui_col, ub_row, ub_col,
                                                     bi_row, E_UI, E_UB, E_BI);
    scan_blocksum_k<<<SB, T, 0, stream>>>(deg, blockSums, RTOT);
    scan_offsets_k<<<1, 64, 0, stream>>>(blockSums, rowptr, SB, RTOT);
    scan_write_k<<<SB, T, 0, stream>>>(deg, blockSums, rowptr, RTOT);
    initgcur_k<<<1, 128, 0, stream>>>(rowptr, gcur);
    binA_k<<<(ETOT + TILE - 1) / TILE, 256, 0, stream>>>(ui_row, ui_col, ub_row, ub_col,
                                                         bi_row, bi_col, E_UI, E_UB, E_BI,
                                                         ETOT, gcur, bbuf);
    binB_k<<<NBKT, 1024, 0, stream>>>(rowptr, bbuf, ebuf);

    // ---- stage1: all four layer-1 pulls ----
    stage1_k<<<(B4 + 3) / 4, T, 0, stream>>>(rowptr, ebuf, U, I, B,
                                             f1u_ui, f1i_ui, f1u_ub, f1b_ub);
    // ---- stage2a: ui-user, ub-user, ub-bundle finalize ----
    stage2a_k<<<(2 * NU + NB + 3) / 4, T, 0, stream>>>(rowptr, ebuf, U, B,
                                                       f1u_ui, f1i_ui, f1u_ub, f1b_ub,
                                                       outU, outB);
    // ---- stage2b: ui-item finalize (in-place acc_i) ----
    stage2b_k<<<(NI + 3) / 4, T, 0, stream>>>(rowptr, ebuf, I, f1u_ui, f1i_ui);
    // ---- stage3: weighted bi aggregation ----
    stage3_k<<<(NB + 3) / 4, T, 0, stream>>>(rowptr, ebuf, f1i_ui, outB);
}

// Round 6
// 625.387 us; speedup vs baseline: 1.7233x; 1.3720x over previous
//
#include <hip/hip_runtime.h>
#include <hip/hip_bf16.h>

// Problem constants (match reference setup_inputs)
#define NU 100000
#define NI 200000
#define NB 50000
#define D  64

// Concatenated CSR row-space: 5 graph directions
#define B0 0
#define B1 (NU)
#define B2 (NU + NI)
#define B3 (2 * NU + NI)
#define B4 (2 * NU + NI + NB)
#define RTOT (2 * NU + NI + 2 * NB)   // 500000 rows total

// Bucketing for the two-phase edge sort
#define BKT_SHIFT 12
#define ROWS_PER_BKT 4096
#define NBKT ((RTOT + ROWS_PER_BKT - 1) / ROWS_PER_BKT)   // 123
#define TILE 4096
#define EPT (TILE / 256)

typedef unsigned short ushort_t;

// ======================= bf16 helpers =======================

__device__ __forceinline__ unsigned f2bf(float f) {
    unsigned u = __float_as_uint(f);
    return (u + 0x7FFFu + ((u >> 16) & 1u)) >> 16;   // RNE
}

__device__ __forceinline__ uint4 pack8(const float* a) {
    uint4 o;
    o.x = f2bf(a[0]) | (f2bf(a[1]) << 16);
    o.y = f2bf(a[2]) | (f2bf(a[3]) << 16);
    o.z = f2bf(a[4]) | (f2bf(a[5]) << 16);
    o.w = f2bf(a[6]) | (f2bf(a[7]) << 16);
    return o;
}

__device__ __forceinline__ void addbf8(uint4 v, float* a) {
    a[0] += __uint_as_float(v.x << 16);
    a[1] += __uint_as_float(v.x & 0xFFFF0000u);
    a[2] += __uint_as_float(v.y << 16);
    a[3] += __uint_as_float(v.y & 0xFFFF0000u);
    a[4] += __uint_as_float(v.z << 16);
    a[5] += __uint_as_float(v.z & 0xFFFF0000u);
    a[6] += __uint_as_float(v.w << 16);
    a[7] += __uint_as_float(v.w & 0xFFFF0000u);
}

// f32 tables -> bf16 tables (one fused launch; 8 elems/thread)
__global__ void cvt_all_k(const float* __restrict__ U, const float* __restrict__ I,
                          const float* __restrict__ Bf,
                          ushort_t* __restrict__ Ubh, ushort_t* __restrict__ Ibh,
                          ushort_t* __restrict__ Bbh) {
    int t = blockIdx.x * blockDim.x + threadIdx.x;
    const int nU = NU * D / 8, nI = NI * D / 8, nB = NB * D / 8;
    const float* s; ushort_t* d;
    if (t < nU)           { s = U;  d = Ubh; }
    else if (t < nU + nI) { s = I;  d = Ibh; t -= nU; }
    else if (t < nU + nI + nB) { s = Bf; d = Bbh; t -= nU + nI; }
    else return;
    const float4 f0 = *reinterpret_cast<const float4*>(s + (size_t)t * 8);
    const float4 f1 = *reinterpret_cast<const float4*>(s + (size_t)t * 8 + 4);
    float a[8] = {f0.x, f0.y, f0.z, f0.w, f1.x, f1.y, f1.z, f1.w};
    *reinterpret_cast<uint4*>(d + (size_t)t * 8) = pack8(a);
}

// ======================= CSR build =======================

__global__ void hist_all_k(int* __restrict__ deg,
                           const int* __restrict__ ui_row, const int* __restrict__ ui_col,
                           const int* __restrict__ ub_row, const int* __restrict__ ub_col,
                           const int* __restrict__ bi_row,
                           int E_UI, int E_UB, int E_BI) {
    int i = blockIdx.x * blockDim.x + threadIdx.x;
    const int* p; int off;
    if (i < E_UI)                     { p = ui_row; off = B0; }
    else if (i < 2 * E_UI)            { p = ui_col; off = B1; i -= E_UI; }
    else if (i < 2 * E_UI + E_UB)     { p = ub_row; off = B2; i -= 2 * E_UI; }
    else if (i < 2 * E_UI + 2 * E_UB) { p = ub_col; off = B3; i -= 2 * E_UI + E_UB; }
    else if (i < 2 * E_UI + 2 * E_UB + E_BI) { p = bi_row; off = B4; i -= 2 * E_UI + 2 * E_UB; }
    else return;
    atomicAdd(&deg[off + p[i]], 1);
}

__global__ void scan_blocksum_k(const int* __restrict__ deg, int* __restrict__ blockSums, int n) {
    int tid = threadIdx.x;
    int base = blockIdx.x * 2048 + tid * 8;
    int sum = 0;
#pragma unroll
    for (int k = 0; k < 8; k++) {
        int idx = base + k;
        if (idx < n) sum += deg[idx];
    }
#pragma unroll
    for (int off = 32; off; off >>= 1) sum += __shfl_down(sum, off, 64);
    __shared__ int ws[4];
    if ((tid & 63) == 0) ws[tid >> 6] = sum;
    __syncthreads();
    if (tid == 0) blockSums[blockIdx.x] = ws[0] + ws[1] + ws[2] + ws[3];
}

__global__ void scan_offsets_k(int* __restrict__ blockSums, int* __restrict__ rowptr,
                               int numBlocks, int n) {
    int lane = threadIdx.x;  // 64 threads
    int nchunk = (numBlocks + 63) / 64;
    int idx0 = lane * nchunk;
    int vals[8];
    int s = 0;
#pragma unroll 4
    for (int k = 0; k < nchunk; k++) {
        int id = idx0 + k;
        vals[k] = (id < numBlocks) ? blockSums[id] : 0;
        s += vals[k];
    }
    int x = s;
#pragma unroll
    for (int off = 1; off < 64; off <<= 1) {
        int y = __shfl_up(x, off, 64);
        if (lane >= off) x += y;
    }
    int excl = x - s;
#pragma unroll 4
    for (int k = 0; k < nchunk; k++) {
        int id = idx0 + k;
        if (id < numBlocks) blockSums[id] = excl;
        excl += vals[k];
    }
    if (lane == 63) rowptr[n] = x;
}

__global__ void scan_write_k(const int* __restrict__ deg, const int* __restrict__ blockSums,
                             int* __restrict__ rowptr, int n) {
    int tid = threadIdx.x;
    int base = blockIdx.x * 2048 + tid * 8;
    int v[8];
    int sum = 0;
#pragma unroll
    for (int k = 0; k < 8; k++) {
        int idx = base + k;
        int d = (idx < n) ? deg[idx] : 0;
        v[k] = sum;
        sum += d;
    }
    int lane = tid & 63, wave = tid >> 6;
    int x = sum;
#pragma unroll
    for (int off = 1; off < 64; off <<= 1) {
        int y = __shfl_up(x, off, 64);
        if (lane >= off) x += y;
    }
    __shared__ int wsum[4];
    if (lane == 63) wsum[wave] = x;
    __syncthreads();
    int woff = 0;
    for (int w = 0; w < wave; w++) woff += wsum[w];
    int thrOff = blockSums[blockIdx.x] + woff + (x - sum);
#pragma unroll
    for (int k = 0; k < 8; k++) {
        int idx = base + k;
        if (idx < n) rowptr[idx] = thrOff + v[k];
    }
}

__global__ void initgcur_k(const int* __restrict__ rowptr, int* __restrict__ gcur) {
    int b = threadIdx.x;
    if (b < 128) {
        int r = b << BKT_SHIFT;
        gcur[b] = rowptr[r < RTOT ? r : RTOT];
    }
}

__device__ __forceinline__ void decode_edge(int i,
        const int* __restrict__ ui_row, const int* __restrict__ ui_col,
        const int* __restrict__ ub_row, const int* __restrict__ ub_col,
        const int* __restrict__ bi_row, const int* __restrict__ bi_col,
        int E_UI, int E_UB, int E_BI, int& gdst, int& src) {
    if (i < E_UI)                     { gdst = B0 + ui_row[i]; src = ui_col[i]; }
    else if (i < 2 * E_UI)            { int j = i - E_UI; gdst = B1 + ui_col[j]; src = ui_row[j]; }
    else if (i < 2 * E_UI + E_UB)     { int j = i - 2 * E_UI; gdst = B2 + ub_row[j]; src = ub_col[j]; }
    else if (i < 2 * E_UI + 2 * E_UB) { int j = i - 2 * E_UI - E_UB; gdst = B3 + ub_col[j]; src = ub_row[j]; }
    else                              { int j = i - 2 * E_UI - 2 * E_UB; gdst = B4 + bi_row[j]; src = bi_col[j]; }
}

// Phase A: tile-local counting sort by coarse bucket; bbuf entry: (src<<12)|(gdst&4095)
__global__ __launch_bounds__(256) void binA_k(
        const int* __restrict__ ui_row, const int* __restrict__ ui_col,
        const int* __restrict__ ub_row, const int* __restrict__ ub_col,
        const int* __restrict__ bi_row, const int* __restrict__ bi_col,
        int E_UI, int E_UB, int E_BI, int ETOT,
        int* __restrict__ gcur, int* __restrict__ bbuf) {
    __shared__ int hist[NBKT], runStart[NBKT], gbase[NBKT], cnt2[NBKT];
    __shared__ int ord[TILE];
    __shared__ int gpos[TILE];
    int tid = threadIdx.x;
    for (int b = tid; b < NBKT; b += 256) { hist[b] = 0; cnt2[b] = 0; }
    __syncthreads();
    int base = blockIdx.x * TILE;
#pragma unroll
    for (int k = 0; k < EPT; k++) {
        int i = base + k * 256 + tid;
        if (i < ETOT) {
            int gdst, src;
            decode_edge(i, ui_row, ui_col, ub_row, ub_col, bi_row, bi_col,
                        E_UI, E_UB, E_BI, gdst, src);
            atomicAdd(&hist[gdst >> BKT_SHIFT], 1);
        }
    }
    __syncthreads();
    if (tid == 0) {
        int run = 0;
        for (int b = 0; b < NBKT; b++) { runStart[b] = run; run += hist[b]; }
    }
    __syncthreads();
    if (tid < NBKT && hist[tid] > 0) gbase[tid] = atomicAdd(&gcur[tid], hist[tid]);
    __syncthreads();
#pragma unroll
    for (int k = 0; k < EPT; k++) {
        int i = base + k * 256 + tid;
        if (i < ETOT) {
            int gdst, src;
            decode_edge(i, ui_row, ui_col, ub_row, ub_col, bi_row, bi_col,
                        E_UI, E_UB, E_BI, gdst, src);
            int b = gdst >> BKT_SHIFT;
            int loc = runStart[b] + atomicAdd(&cnt2[b], 1);
            ord[loc] = (src << BKT_SHIFT) | (gdst & (ROWS_PER_BKT - 1));
            gpos[loc] = gbase[b] + (loc - runStart[b]);
        }
    }
    __syncthreads();
    int tcnt = runStart[NBKT - 1] + hist[NBKT - 1];
    for (int i = tid; i < tcnt; i += 256) bbuf[gpos[i]] = ord[i];
}

// Phase B: per-bucket row placement; ebuf entry = src byte offset for bf16 rows (src*128)
__global__ __launch_bounds__(1024) void binB_k(const int* __restrict__ rowptr,
                                               const int* __restrict__ bbuf,
                                               int* __restrict__ ebuf) {
    __shared__ int lcur[ROWS_PER_BKT];
    int bkt = blockIdx.x;
    int rbase = bkt << BKT_SHIFT;
    int rend = rbase + ROWS_PER_BKT;
    if (rend > RTOT) rend = RTOT;
    int nrows = rend - rbase;
    for (int r = threadIdx.x; r < nrows; r += 1024) lcur[r] = rowptr[rbase + r];
    __syncthreads();
    int s = rowptr[rbase], e = rowptr[rend];
    for (int i = s + (int)threadIdx.x; i < e; i += 1024) {
        int entry = bbuf[i];
        int r = entry & (ROWS_PER_BKT - 1);
        int pos = atomicAdd(&lcur[r], 1);
        ebuf[pos] = (entry >> BKT_SHIFT) << 7;
    }
}

// ======================= pull machinery (bf16, 8 lanes/row) =======================
// wave = 8 rows; lane l: group = l>>3 (row), q = (l&7)*16B (8 dims as bf16x8).

__device__ __forceinline__ void pull8(int s, int e, const int* __restrict__ ebuf,
                                      const char* __restrict__ baseq, float* a) {
    int j = s;
    for (; j + 3 < e; j += 4) {
        int c0 = ebuf[j], c1 = ebuf[j + 1], c2 = ebuf[j + 2], c3 = ebuf[j + 3];
        uint4 v0 = *reinterpret_cast<const uint4*>(baseq + c0);
        uint4 v1 = *reinterpret_cast<const uint4*>(baseq + c1);
        uint4 v2 = *reinterpret_cast<const uint4*>(baseq + c2);
        uint4 v3 = *reinterpret_cast<const uint4*>(baseq + c3);
        addbf8(v0, a); addbf8(v1, a); addbf8(v2, a); addbf8(v3, a);
    }
    for (; j < e; ++j) {
        uint4 v = *reinterpret_cast<const uint4*>(baseq + ebuf[j]);
        addbf8(v, a);
    }
}

__device__ __forceinline__ float rowsum8(float s) {
    s += __shfl_xor(s, 1, 64);
    s += __shfl_xor(s, 2, 64);
    s += __shfl_xor(s, 4, 64);
    return s;
}

// stage1: all four layer-1 pulls fused; bf16 in, bf16 out, no cross-lane needed
__global__ void stage1_k(const int* __restrict__ rowptr, const int* __restrict__ ebuf,
                         const ushort_t* __restrict__ Ubh, const ushort_t* __restrict__ Ibh,
                         const ushort_t* __restrict__ Bbh,
                         ushort_t* __restrict__ f1u_ui, ushort_t* __restrict__ f1i_ui,
                         ushort_t* __restrict__ f1u_ub, ushort_t* __restrict__ f1b_ub) {
    int gr = blockIdx.x * 32 + (threadIdx.x >> 3);
    if (gr >= B4) return;
    int q = (threadIdx.x & 7) << 4;
    const ushort_t* src; ushort_t* dst; int row;
    if (gr < B1)      { src = Ibh; dst = f1u_ui; row = gr; }
    else if (gr < B2) { src = Ubh; dst = f1i_ui; row = gr - B1; }
    else if (gr < B3) { src = Bbh; dst = f1u_ub; row = gr - B2; }
    else              { src = Ubh; dst = f1b_ub; row = gr - B3; }
    int s = rowptr[gr], e = rowptr[gr + 1];
    float a[8] = {0, 0, 0, 0, 0, 0, 0, 0};
    pull8(s, e, ebuf, (const char*)src + q, a);
    *reinterpret_cast<uint4*>((char*)dst + (size_t)row * 128 + q) = pack8(a);
}

// finalize: out(f32) = base + l2norm(self) + l2norm(acc)
__device__ __forceinline__ void fin8_f32(const float* a, const ushort_t* selfbh,
                                         const float* basef, float* out, int row, int l) {
    int q = l << 4;
    uint4 sv = *reinterpret_cast<const uint4*>((const char*)selfbh + (size_t)row * 128 + q);
    float v[8] = {0, 0, 0, 0, 0, 0, 0, 0};
    addbf8(sv, v);
    float s1 = 0.f, s2 = 0.f;
#pragma unroll
    for (int k = 0; k < 8; k++) { s1 = fmaf(v[k], v[k], s1); s2 = fmaf(a[k], a[k], s2); }
    s1 = rowsum8(s1);
    s2 = rowsum8(s2);
    float i1 = 1.0f / fmaxf(sqrtf(s1), 1e-12f);
    float i2 = 1.0f / fmaxf(sqrtf(s2), 1e-12f);
    const float4 b0 = *reinterpret_cast<const float4*>(basef + (size_t)row * D + l * 8);
    const float4 b1 = *reinterpret_cast<const float4*>(basef + (size_t)row * D + l * 8 + 4);
    float4 o0, o1;
    o0.x = b0.x + v[0] * i1 + a[0] * i2;
    o0.y = b0.y + v[1] * i1 + a[1] * i2;
    o0.z = b0.z + v[2] * i1 + a[2] * i2;
    o0.w = b0.w + v[3] * i1 + a[3] * i2;
    o1.x = b1.x + v[4] * i1 + a[4] * i2;
    o1.y = b1.y + v[5] * i1 + a[5] * i2;
    o1.z = b1.z + v[6] * i1 + a[6] * i2;
    o1.w = b1.w + v[7] * i1 + a[7] * i2;
    *reinterpret_cast<float4*>(out + (size_t)row * 128 + l * 8) = o0;
    *reinterpret_cast<float4*>(out + (size_t)row * 128 + l * 8 + 4) = o1;
}

// stage2a: ui-user, ub-user, ub-bundle finalize fused -> f32 outputs
__global__ void stage2a_k(const int* __restrict__ rowptr, const int* __restrict__ ebuf,
                          const float* __restrict__ U, const float* __restrict__ Bf,
                          const ushort_t* __restrict__ f1u_ui, const ushort_t* __restrict__ f1i_ui,
                          const ushort_t* __restrict__ f1u_ub, const ushort_t* __restrict__ f1b_ub,
                          float* __restrict__ outU, float* __restrict__ outB) {
    int t = blockIdx.x * 32 + (threadIdx.x >> 3);
    if (t >= 2 * NU + NB) return;
    int l = threadIdx.x & 7;
    int q = l << 4;
    int cr, row; const ushort_t* src; const ushort_t* self; const float* basef; float* out;
    if (t < NU)          { cr = t;               src = f1i_ui; self = f1u_ui; basef = U;  out = outU;      row = t; }
    else if (t < 2 * NU) { cr = B2 + t - NU;     src = f1b_ub; self = f1u_ub; basef = U;  out = outU + 64; row = t - NU; }
    else                 { cr = B3 + t - 2 * NU; src = f1u_ub; self = f1b_ub; basef = Bf; out = outB + 64; row = t - 2 * NU; }
    int s = rowptr[cr], e = rowptr[cr + 1];
    float a[8] = {0, 0, 0, 0, 0, 0, 0, 0};
    pull8(s, e, ebuf, (const char*)src + q, a);
    fin8_f32(a, self, basef, out, row, l);
}

// stage2b: ui-item finalize; acc_i written IN PLACE (bf16) over f1i_ui
__global__ void stage2b_k(const int* __restrict__ rowptr, const int* __restrict__ ebuf,
                          const float* __restrict__ I, const ushort_t* __restrict__ f1u_ui,
                          ushort_t* __restrict__ f1i_ui) {
    int t = blockIdx.x * 32 + (threadIdx.x >> 3);
    if (t >= NI) return;
    int l = threadIdx.x & 7;
    int q = l << 4;
    int s = rowptr[B1 + t], e = rowptr[B1 + t + 1];
    float a[8] = {0, 0, 0, 0, 0, 0, 0, 0};
    pull8(s, e, ebuf, (const char*)f1u_ui + q, a);
    uint4 sv = *reinterpret_cast<const uint4*>((const char*)f1i_ui + (size_t)t * 128 + q);
    float v[8] = {0, 0, 0, 0, 0, 0, 0, 0};
    addbf8(sv, v);
    float s1 = 0.f, s2 = 0.f;
#pragma unroll
    for (int k = 0; k < 8; k++) { s1 = fmaf(v[k], v[k], s1); s2 = fmaf(a[k], a[k], s2); }
    s1 = rowsum8(s1);
    s2 = rowsum8(s2);
    float i1 = 1.0f / fmaxf(sqrtf(s1), 1e-12f);
    float i2 = 1.0f / fmaxf(sqrtf(s2), 1e-12f);
    const float4 b0 = *reinterpret_cast<const float4*>(I + (size_t)t * D + l * 8);
    const float4 b1 = *reinterpret_cast<const float4*>(I + (size_t)t * D + l * 8 + 4);
    float o[8];
    o[0] = b0.x + v[0] * i1 + a[0] * i2;
    o[1] = b0.y + v[1] * i1 + a[1] * i2;
    o[2] = b0.z + v[2] * i1 + a[2] * i2;
    o[3] = b0.w + v[3] * i1 + a[3] * i2;
    o[4] = b1.x + v[4] * i1 + a[4] * i2;
    o[5] = b1.y + v[5] * i1 + a[5] * i2;
    o[6] = b1.z + v[6] * i1 + a[6] * i2;
    o[7] = b1.w + v[7] * i1 + a[7] * i2;
    *reinterpret_cast<uint4*>((char*)f1i_ui + (size_t)t * 128 + q) = pack8(o);
}

// stage3: weighted bi aggregation from bf16 acc_i -> outB[:,0:64] (f32)
__global__ void stage3_k(const int* __restrict__ rowptr, const int* __restrict__ ebuf,
                         const ushort_t* __restrict__ acc_i, float* __restrict__ outB) {
    int t = blockIdx.x * 32 + (threadIdx.x >> 3);
    if (t >= NB) return;
    int l = threadIdx.x & 7;
    int q = l << 4;
    int s = rowptr[B4 + t], e = rowptr[B4 + t + 1];
    float a[8] = {0, 0, 0, 0, 0, 0, 0, 0};
    pull8(s, e, ebuf, (const char*)acc_i + q, a);
    float w = 1.0f / ((float)(e - s) + 1e-8f);
    float4 o0 = {a[0] * w, a[1] * w, a[2] * w, a[3] * w};
    float4 o1 = {a[4] * w, a[5] * w, a[6] * w, a[7] * w};
    *reinterpret_cast<float4*>(outB + (size_t)t * 128 + l * 8) = o0;
    *reinterpret_cast<float4*>(outB + (size_t)t * 128 + l * 8 + 4) = o1;
}

extern "C" void kernel_launch(void* const* d_in, const int* in_sizes, int n_in,
                              void* d_out, int out_size, void* d_ws, size_t ws_size,
                              hipStream_t stream) {
    const float* U = (const float*)d_in[0];
    const float* I = (const float*)d_in[1];
    const float* B = (const float*)d_in[2];
    const int* ui_row = (const int*)d_in[3];
    const int* ui_col = (const int*)d_in[4];
    const int* ub_row = (const int*)d_in[5];
    const int* ub_col = (const int*)d_in[6];
    const int* bi_row = (const int*)d_in[7];
    const int* bi_col = (const int*)d_in[8];
    const int E_UI = in_sizes[3], E_UB = in_sizes[5], E_BI = in_sizes[7];
    const int ETOT = 2 * E_UI + 2 * E_UB + E_BI;

    // workspace layout (~142 MB): bf16 tables + bf16 intermediates + CSR
    ushort_t* Ubh    = (ushort_t*)d_ws;                 // NU*D
    ushort_t* Ibh    = Ubh + (size_t)NU * D;            // NI*D
    ushort_t* Bbh    = Ibh + (size_t)NI * D;            // NB*D
    ushort_t* f1u_ui = Bbh + (size_t)NB * D;            // NU*D
    ushort_t* f1i_ui = f1u_ui + (size_t)NU * D;         // NI*D (becomes acc_i)
    ushort_t* f1u_ub = f1i_ui + (size_t)NI * D;         // NU*D
    ushort_t* f1b_ub = f1u_ub + (size_t)NU * D;         // NB*D
    int* deg       = (int*)(f1b_ub + (size_t)NB * D);   // RTOT
    int* rowptr    = deg + RTOT;                        // RTOT+1
    int* blockSums = rowptr + (RTOT + 1);               // 256
    int* gcur      = blockSums + 256;                   // 128
    int* ebuf      = gcur + 128;                        // ETOT
    int* bbuf      = ebuf + ETOT;                       // ETOT

    float* outU = (float*)d_out;            // NU x 128 (IL_u | BL_u)
    float* outB = outU + (size_t)NU * 128;  // NB x 128 (IL_b | BL_b)

    const int T = 256;
    const int SB = (RTOT + 2047) / 2048;
    const int NCVT = (NU + NI + NB) * D / 8;

    // ---- bf16 table conversion ----
    cvt_all_k<<<(NCVT + T - 1) / T, T, 0, stream>>>(U, I, B, Ubh, Ibh, Bbh);

    // ---- CSR build ----
    hipMemsetAsync(deg, 0, RTOT * sizeof(int), stream);
    hist_all_k<<<(ETOT + T - 1) / T, T, 0, stream>>>(deg, ui_row, ui_col, ub_row, ub_col,
                                                     bi_row, E_UI, E_UB, E_BI);
    scan_blocksum_k<<<SB, T, 0, stream>>>(deg, blockSums, RTOT);
    scan_offsets_k<<<1, 64, 0, stream>>>(blockSums, rowptr, SB, RTOT);
    scan_write_k<<<SB, T, 0, stream>>>(deg, blockSums, rowptr, RTOT);
    initgcur_k<<<1, 128, 0, stream>>>(rowptr, gcur);
    binA_k<<<(ETOT + TILE - 1) / TILE, 256, 0, stream>>>(ui_row, ui_col, ub_row, ub_col,
                                                         bi_row, bi_col, E_UI, E_UB, E_BI,
                                                         ETOT, gcur, bbuf);
    binB_k<<<NBKT, 1024, 0, stream>>>(rowptr, bbuf, ebuf);

    // ---- stage1: all four layer-1 pulls ----
    stage1_k<<<(B4 + 31) / 32, T, 0, stream>>>(rowptr, ebuf, Ubh, Ibh, Bbh,
                                               f1u_ui, f1i_ui, f1u_ub, f1b_ub);
    // ---- stage2a: ui-user, ub-user, ub-bundle finalize ----
    stage2a_k<<<(2 * NU + NB + 31) / 32, T, 0, stream>>>(rowptr, ebuf, U, B,
                                                         f1u_ui, f1i_ui, f1u_ub, f1b_ub,
                                                         outU, outB);
    // ---- stage2b: ui-item finalize (in-place bf16 acc_i) ----
    stage2b_k<<<(NI + 31) / 32, T, 0, stream>>>(rowptr, ebuf, I, f1u_ui, f1i_ui);
    // ---- stage3: weighted bi aggregation ----
    stage3_k<<<(NB + 31) / 32, T, 0, stream>>>(rowptr, ebuf, f1i_ui, outB);
}